// Round 2
// baseline (646.384 us; speedup 1.0000x reference)
//
#include <hip/hip_runtime.h>

typedef __bf16 bf16x8 __attribute__((ext_vector_type(8)));
typedef float f32x4 __attribute__((ext_vector_type(4)));
typedef unsigned short u16x8 __attribute__((ext_vector_type(8)));
typedef unsigned short us;

#define MM 2048
#define TT 4096

__device__ __forceinline__ us f2bf(float f){
  unsigned int u = __builtin_bit_cast(unsigned int, f);
  u = (u + 0x7fffu + ((u >> 16) & 1u)) >> 16;
  return (us)u;
}
__device__ __forceinline__ float bf2f(us u){
  unsigned int x = ((unsigned int)u) << 16;
  return __builtin_bit_cast(float, x);
}
__device__ __forceinline__ void store_out(us* p, float v){ *p = f2bf(v); }
__device__ __forceinline__ void store_out(float* p, float v){ *p = v; }

// ---------------- fp32 -> bf16 hi/lo split (n = grid*256*8 elements) ----------------
__global__ __launch_bounds__(256) void split_cast(const float* __restrict__ in,
                                                  us* __restrict__ hi, us* __restrict__ lo){
  size_t i = ((size_t)blockIdx.x * 256 + threadIdx.x) * 8;
  float4 a = *(const float4*)(in + i);
  float4 b = *(const float4*)(in + i + 4);
  float v[8] = {a.x,a.y,a.z,a.w,b.x,b.y,b.z,b.w};
  u16x8 rh, rl;
  for (int j = 0; j < 8; j++){
    us h = f2bf(v[j]);
    rh[j] = h;
    rl[j] = f2bf(v[j] - bf2f(h));
  }
  *(u16x8*)(hi + i) = rh;
  *(u16x8*)(lo + i) = rl;
}

// ---------------- transpose + split: W[K][N] f32 -> Wt_hi/lo[N][K] bf16 ----------------
__global__ __launch_bounds__(256) void transpose_split(const float* __restrict__ W,
                                                       us* __restrict__ Wth, us* __restrict__ Wtl,
                                                       int K, int N){
  __shared__ float tile[32][33];
  int tx = threadIdx.x & 31, ty = threadIdx.x >> 5;   // 32 x 8
  int n0 = blockIdx.x * 32, k0 = blockIdx.y * 32;
  for (int r = 0; r < 32; r += 8)
    tile[ty + r][tx] = W[(size_t)(k0 + ty + r) * N + n0 + tx];
  __syncthreads();
  for (int r = 0; r < 32; r += 8){
    float v = tile[tx][ty + r];
    us h = f2bf(v);
    size_t idx = (size_t)(n0 + ty + r) * K + k0 + tx;
    Wth[idx] = h;
    Wtl[idx] = f2bf(v - bf2f(h));
  }
}

// ---------------- bf16 GEMM, B pre-transposed (Bt[N=1024][K]), +bias ----------------
// 128x128 tile, BK=32, 4 waves (2x2), per-wave 64x64 (4x4 frags of 16x16x32 MFMA)
// SPLIT_IN: acc = Ah*Bh + Ah*Bl + Al*Bh. SPLIT_OUT: writes hi/lo bf16 pair.
// Output row remap: in-row r (0..4095) -> (r>>11)*bstride + roff + (r&2047); out ld = 1024.
template<bool SPLIT_IN, bool SPLIT_OUT, typename OutT>
__global__ __launch_bounds__(256) void gemm_bt(const us* __restrict__ Ah, const us* __restrict__ Al,
                                               const us* __restrict__ Bth, const us* __restrict__ Btl,
                                               const float* __restrict__ bias,
                                               OutT* __restrict__ Co, us* __restrict__ Clo,
                                               int Kk, int bstride, int roff){
  __shared__ us sm[SPLIT_IN ? 16384 : 8192];  // Ah@0, Bh@4096, (Al@8192, Bl@12288)
  const int tid = threadIdx.x, wid = tid >> 6, lane = tid & 63;
  const int l15 = lane & 15, l16 = lane >> 4;
  const int row0 = blockIdx.y * 128, col0 = blockIdx.x * 128;
  const int wr = (wid >> 1) * 64, wc = (wid & 1) * 64;
  f32x4 acc[4][4] = {};

  for (int k0 = 0; k0 < Kk; k0 += 32){
    for (int c = 0; c < 2; ++c){
      int i = c * 256 + tid;                           // 0..511: row=i>>2, k8=(i&3)*8
      size_t aoff = (size_t)(row0 + (i >> 2)) * Kk + k0 + (i & 3) * 8;
      size_t boff = (size_t)(col0 + (i >> 2)) * Kk + k0 + (i & 3) * 8;
      __builtin_amdgcn_global_load_lds((const __attribute__((address_space(1))) unsigned int*)(Ah + aoff),
        (__attribute__((address_space(3))) unsigned int*)&sm[c * 2048 + wid * 512], 16, 0, 0);
      __builtin_amdgcn_global_load_lds((const __attribute__((address_space(1))) unsigned int*)(Bth + boff),
        (__attribute__((address_space(3))) unsigned int*)&sm[4096 + c * 2048 + wid * 512], 16, 0, 0);
      if (SPLIT_IN){
        __builtin_amdgcn_global_load_lds((const __attribute__((address_space(1))) unsigned int*)(Al + aoff),
          (__attribute__((address_space(3))) unsigned int*)&sm[8192 + c * 2048 + wid * 512], 16, 0, 0);
        __builtin_amdgcn_global_load_lds((const __attribute__((address_space(1))) unsigned int*)(Btl + boff),
          (__attribute__((address_space(3))) unsigned int*)&sm[12288 + c * 2048 + wid * 512], 16, 0, 0);
      }
    }
    __syncthreads();
    bf16x8 afh[4], bfh[4];
    for (int m = 0; m < 4; m++) afh[m] = *(const bf16x8*)&sm[(wr + m * 16 + l15) * 32 + l16 * 8];
    for (int n = 0; n < 4; n++) bfh[n] = *(const bf16x8*)&sm[4096 + (wc + n * 16 + l15) * 32 + l16 * 8];
    if (SPLIT_IN){
      bf16x8 afl[4], bfl[4];
      for (int m = 0; m < 4; m++) afl[m] = *(const bf16x8*)&sm[8192 + (wr + m * 16 + l15) * 32 + l16 * 8];
      for (int n = 0; n < 4; n++) bfl[n] = *(const bf16x8*)&sm[12288 + (wc + n * 16 + l15) * 32 + l16 * 8];
      for (int m = 0; m < 4; m++)
        for (int n = 0; n < 4; n++){
          acc[m][n] = __builtin_amdgcn_mfma_f32_16x16x32_bf16(afh[m], bfh[n], acc[m][n], 0, 0, 0);
          acc[m][n] = __builtin_amdgcn_mfma_f32_16x16x32_bf16(afh[m], bfl[n], acc[m][n], 0, 0, 0);
          acc[m][n] = __builtin_amdgcn_mfma_f32_16x16x32_bf16(afl[m], bfh[n], acc[m][n], 0, 0, 0);
        }
    } else {
      for (int m = 0; m < 4; m++)
        for (int n = 0; n < 4; n++)
          acc[m][n] = __builtin_amdgcn_mfma_f32_16x16x32_bf16(afh[m], bfh[n], acc[m][n], 0, 0, 0);
    }
    __syncthreads();
  }

  for (int m = 0; m < 4; m++)
    for (int n = 0; n < 4; n++){
      int col = col0 + wc + n * 16 + l15;
      float bv = bias[col];
      for (int j = 0; j < 4; j++){
        int r = row0 + wr + m * 16 + l16 * 4 + j;
        size_t orow = (size_t)((r >> 11) * bstride + roff + (r & 2047));
        float v = acc[m][n][j] + bv;
        if (SPLIT_OUT){
          us h = f2bf(v);
          ((us*)Co)[orow * 1024 + col] = h;
          Clo[orow * 1024 + col] = f2bf(v - bf2f(h));
        } else {
          store_out(&Co[orow * 1024 + col], v);
        }
      }
    }
}

// ---------------- fused attention (split-precision QK^T) ----------------
// grid: B*H*(M/64) blocks; 4 waves; wave w owns q rows [w*16, w*16+16)
__global__ __launch_bounds__(256) void attn_kernel(const us* __restrict__ Qh, const us* __restrict__ Ql,
                                                   const us* __restrict__ Kh, const us* __restrict__ Kl,
                                                   const us* __restrict__ Vb,
                                                   us* __restrict__ attno){
  __shared__ us Klh[64 * 72];
  __shared__ us Kll[64 * 72];
  __shared__ us Vt[64 * 72];
  __shared__ us Pl[4][16 * 72];
  const int tid = threadIdx.x, wid = tid >> 6, lane = tid & 63;
  const int l15 = lane & 15, l16 = lane >> 4;
  const int bid = blockIdx.x;
  const int qt = bid & 31;            // q-tile (M/64 = 32)
  const int bh = bid >> 5;
  const int h = bh & 15, b = bh >> 4;

  // Q fragments (A operand), hoisted: rows qt*64 + wid*16 + l15, k = d
  bf16x8 qfh[2], qfl[2];
  {
    size_t qoff = (size_t)(b * MM + qt * 64 + wid * 16 + l15) * 1024 + h * 64 + l16 * 8;
    qfh[0] = *(const bf16x8*)(Qh + qoff);
    qfh[1] = *(const bf16x8*)(Qh + qoff + 32);
    qfl[0] = *(const bf16x8*)(Ql + qoff);
    qfl[1] = *(const bf16x8*)(Ql + qoff + 32);
  }

  f32x4 acc[4] = {};
  float mrow[4], lrow[4];
  for (int j = 0; j < 4; j++){ mrow[j] = -1e30f; lrow[j] = 0.f; }

  for (int t0 = 0; t0 < TT; t0 += 64){
    size_t krow = ((size_t)(b * TT + t0)) * 1024 + h * 64;
    __syncthreads();   // previous tile's LDS reads done
    for (int rep = 0; rep < 2; ++rep){
      int i = rep * 256 + tid;            // 0..511 -> t = i/8, d8 = (i%8)*8
      int t = i >> 3, d8 = (i & 7) * 8;
      size_t g = krow + (size_t)t * 1024 + d8;
      *(uint4*)&Klh[t * 72 + d8] = *(const uint4*)(Kh + g);
      *(uint4*)&Kll[t * 72 + d8] = *(const uint4*)(Kl + g);
      uint4 v4 = *(const uint4*)(Vb + g);
      const us* s = (const us*)&v4;
      for (int jj = 0; jj < 8; jj++) Vt[(d8 + jj) * 72 + t] = s[jj];
    }
    __syncthreads();

    // S = Q K^T  with split precision: QhKh + QhKl + QlKh
    f32x4 sfr[4] = {};
    for (int kk = 0; kk < 2; kk++){
      for (int n = 0; n < 4; n++){
        bf16x8 kfh = *(const bf16x8*)&Klh[(n * 16 + l15) * 72 + kk * 32 + l16 * 8];
        bf16x8 kfl = *(const bf16x8*)&Kll[(n * 16 + l15) * 72 + kk * 32 + l16 * 8];
        sfr[n] = __builtin_amdgcn_mfma_f32_16x16x32_bf16(qfh[kk], kfh, sfr[n], 0, 0, 0);
        sfr[n] = __builtin_amdgcn_mfma_f32_16x16x32_bf16(qfh[kk], kfl, sfr[n], 0, 0, 0);
        sfr[n] = __builtin_amdgcn_mfma_f32_16x16x32_bf16(qfl[kk], kfh, sfr[n], 0, 0, 0);
      }
    }

    // online softmax (rows j: q = wid*16 + l16*4 + j; cols across n-frags + 16 lanes)
    for (int n = 0; n < 4; n++)
      for (int j = 0; j < 4; j++) sfr[n][j] *= 0.125f;
    for (int j = 0; j < 4; j++){
      float v = fmaxf(fmaxf(sfr[0][j], sfr[1][j]), fmaxf(sfr[2][j], sfr[3][j]));
      for (int msk = 1; msk < 16; msk <<= 1) v = fmaxf(v, __shfl_xor(v, msk, 64));
      float mn = fmaxf(mrow[j], v);
      float rs = __expf(mrow[j] - mn);
      mrow[j] = mn;
      float ts = 0.f;
      for (int n = 0; n < 4; n++){ float p = __expf(sfr[n][j] - mn); sfr[n][j] = p; ts += p; }
      for (int msk = 1; msk < 16; msk <<= 1) ts += __shfl_xor(ts, msk, 64);
      lrow[j] = lrow[j] * rs + ts;
      for (int n = 0; n < 4; n++) acc[n][j] *= rs;
    }

    // P -> LDS (C-layout -> A-layout round trip), per-wave region
    for (int n = 0; n < 4; n++)
      for (int j = 0; j < 4; j++)
        Pl[wid][(l16 * 4 + j) * 72 + n * 16 + l15] = f2bf(sfr[n][j]);
    __syncthreads();

    // PV: out[q][d] += P[q][t] V[t][d]
    for (int kk = 0; kk < 2; kk++){
      bf16x8 pf = *(const bf16x8*)&Pl[wid][l15 * 72 + kk * 32 + l16 * 8];
      for (int n = 0; n < 4; n++){
        bf16x8 vf = *(const bf16x8*)&Vt[(n * 16 + l15) * 72 + kk * 32 + l16 * 8];
        acc[n] = __builtin_amdgcn_mfma_f32_16x16x32_bf16(pf, vf, acc[n], 0, 0, 0);
      }
    }
  }

  for (int n = 0; n < 4; n++)
    for (int j = 0; j < 4; j++){
      size_t row = (size_t)(b * MM + qt * 64 + wid * 16 + l16 * 4 + j);
      attno[row * 1024 + h * 64 + n * 16 + l15] = f2bf(acc[n][j] / lrow[j]);
    }
}

extern "C" void kernel_launch(void* const* d_in, const int* in_sizes, int n_in,
                              void* d_out, int out_size, void* d_ws, size_t ws_size,
                              hipStream_t stream){
  const float* x      = (const float*)d_in[0];
  const float* data   = (const float*)d_in[1];
  const float* W_attn = (const float*)d_in[2];
  const float* b_attn = (const float*)d_in[3];
  const float* W_data = (const float*)d_in[4];
  const float* b_data = (const float*)d_in[5];
  const float* W_proj = (const float*)d_in[6];
  const float* b_proj = (const float*)d_in[7];
  float* out = (float*)d_out;

  char* ws = (char*)d_ws;
  us* xb_hi  = (us*)(ws + 0);            // 4096x1024 (8 MB each)
  us* xb_lo  = (us*)(ws + 8388608);
  us* db_hi  = (us*)(ws + 16777216);
  us* db_lo  = (us*)(ws + 25165824);
  us* Wat_hi = (us*)(ws + 33554432);     // 3072x1024 (6 MB each)
  us* Wat_lo = (us*)(ws + 39845888);
  us* Wdt_hi = (us*)(ws + 46137344);     // 2048x1024 (4 MB each)
  us* Wdt_lo = (us*)(ws + 50331648);
  us* Wpt_hi = (us*)(ws + 54525952);     // 1024x1024 (2 MB each)
  us* Wpt_lo = (us*)(ws + 56623104);
  us* Qh     = (us*)(ws + 58720256);     // [2][2048][1024] (8 MB each)
  us* Ql     = (us*)(ws + 67108864);
  us* Kh     = (us*)(ws + 75497472);     // [2][4096][1024] (16 MB each)
  us* Kl     = (us*)(ws + 92274688);
  us* Vb     = (us*)(ws + 109051904);    // [2][4096][1024] (16 MB)
  us* attno  = (us*)(ws + 16777216);     // alias db_hi (db consumed before attn runs)

  split_cast<<<2048, 256, 0, stream>>>(x, xb_hi, xb_lo);
  split_cast<<<2048, 256, 0, stream>>>(data, db_hi, db_lo);
  transpose_split<<<dim3(96, 32), 256, 0, stream>>>(W_attn, Wat_hi, Wat_lo, 1024, 3072);
  transpose_split<<<dim3(64, 32), 256, 0, stream>>>(W_data, Wdt_hi, Wdt_lo, 1024, 2048);
  transpose_split<<<dim3(32, 32), 256, 0, stream>>>(W_proj, Wpt_hi, Wpt_lo, 1024, 1024);

  dim3 gg(8, 32);
  // q = x @ W_attn[:,0:1024]  (split in+out) -> Qh/Ql [2][2048][1024]
  gemm_bt<true, true, us><<<gg, 256, 0, stream>>>(xb_hi, xb_lo, Wat_hi, Wat_lo,
                                                  b_attn, Qh, Ql, 1024, 2048, 0);
  // k = x @ W_attn[:,1024:2048] -> Kh/Kl rows b*4096 + m
  gemm_bt<true, true, us><<<gg, 256, 0, stream>>>(xb_hi, xb_lo, Wat_hi + 1024 * 1024, Wat_lo + 1024 * 1024,
                                                  b_attn + 1024, Kh, Kl, 1024, 4096, 0);
  // v = x @ W_attn[:,2048:3072] (plain) -> Vb rows b*4096 + m
  gemm_bt<false, false, us><<<gg, 256, 0, stream>>>(xb_hi, nullptr, Wat_hi + 2048 * 1024, nullptr,
                                                    b_attn + 2048, Vb, nullptr, 1024, 4096, 0);
  // k_data = data @ W_data[:,0:1024] -> Kh/Kl rows b*4096 + 2048 + n
  gemm_bt<true, true, us><<<gg, 256, 0, stream>>>(db_hi, db_lo, Wdt_hi, Wdt_lo,
                                                  b_data, Kh, Kl, 1024, 4096, 2048);
  // v_data = data @ W_data[:,1024:2048] (plain) -> Vb rows b*4096 + 2048 + n
  gemm_bt<false, false, us><<<gg, 256, 0, stream>>>(db_hi, nullptr, Wdt_hi + 1024 * 1024, nullptr,
                                                    b_data + 1024, Vb, nullptr, 1024, 4096, 2048);

  attn_kernel<<<1024, 256, 0, stream>>>(Qh, Ql, Kh, Kl, Vb, attno);

  gemm_bt<false, false, float><<<gg, 256, 0, stream>>>(attno, nullptr, Wpt_hi, nullptr,
                                                       b_proj, out, nullptr, 1024, 2048, 0);
}

// Round 3
// 475.010 us; speedup vs baseline: 1.3608x; 1.3608x over previous
//
#include <hip/hip_runtime.h>

typedef __bf16 bf16x8 __attribute__((ext_vector_type(8)));
typedef float f32x4 __attribute__((ext_vector_type(4)));
typedef unsigned short u16x8 __attribute__((ext_vector_type(8)));
typedef unsigned short u16x4 __attribute__((ext_vector_type(4)));
typedef unsigned short us;

#define MM 2048
#define TT 4096

__device__ __forceinline__ us f2bf(float f){
  unsigned int u = __builtin_bit_cast(unsigned int, f);
  u = (u + 0x7fffu + ((u >> 16) & 1u)) >> 16;
  return (us)u;
}
__device__ __forceinline__ float bf2f(us u){
  unsigned int x = ((unsigned int)u) << 16;
  return __builtin_bit_cast(float, x);
}
__device__ __forceinline__ void store_out(us* p, float v){ *p = f2bf(v); }
__device__ __forceinline__ void store_out(float* p, float v){ *p = v; }

// ---------------- fp32 -> bf16 hi/lo split ----------------
__global__ __launch_bounds__(256) void split_cast(const float* __restrict__ in,
                                                  us* __restrict__ hi, us* __restrict__ lo){
  size_t i = ((size_t)blockIdx.x * 256 + threadIdx.x) * 8;
  float4 a = *(const float4*)(in + i);
  float4 b = *(const float4*)(in + i + 4);
  float v[8] = {a.x,a.y,a.z,a.w,b.x,b.y,b.z,b.w};
  u16x8 rh, rl;
  for (int j = 0; j < 8; j++){
    us h = f2bf(v[j]);
    rh[j] = h;
    rl[j] = f2bf(v[j] - bf2f(h));
  }
  *(u16x8*)(hi + i) = rh;
  *(u16x8*)(lo + i) = rl;
}

// ---------------- transpose + split: W[K][N] f32 -> Wt_hi/lo[N][K] bf16 ----------------
__global__ __launch_bounds__(256) void transpose_split(const float* __restrict__ W,
                                                       us* __restrict__ Wth, us* __restrict__ Wtl,
                                                       int K, int N){
  __shared__ float tile[32][33];
  int tx = threadIdx.x & 31, ty = threadIdx.x >> 5;   // 32 x 8
  int n0 = blockIdx.x * 32, k0 = blockIdx.y * 32;
  for (int r = 0; r < 32; r += 8)
    tile[ty + r][tx] = W[(size_t)(k0 + ty + r) * N + n0 + tx];
  __syncthreads();
  for (int r = 0; r < 32; r += 8){
    float v = tile[tx][ty + r];
    us h = f2bf(v);
    size_t idx = (size_t)(n0 + ty + r) * K + k0 + tx;
    Wth[idx] = h;
    Wtl[idx] = f2bf(v - bf2f(h));
  }
}

// ---------------- bf16 GEMM, B pre-transposed (Bt[N][K]), +bias ----------------
// 128x128 tile, BK=32, 4 waves (2x2), per-wave 64x64 (4x4 frags of 16x16x32 MFMA)
// SPLIT_IN: acc = Ah*Bh + Ah*Bl + Al*Bh. SPLIT_OUT: hi/lo bf16 pair.
// TRANS_OUT: write C^T into [2][1024][4096] (planes by r>>11, t = roff + (r&2047)).
// else: out row = (r>>11)*bstride + roff + (r&2047), ld 1024.
template<bool SPLIT_IN, bool SPLIT_OUT, bool TRANS_OUT, typename OutT>
__global__ __launch_bounds__(256) void gemm_bt(const us* __restrict__ Ah, const us* __restrict__ Al,
                                               const us* __restrict__ Bth, const us* __restrict__ Btl,
                                               const float* __restrict__ bias,
                                               OutT* __restrict__ Co, us* __restrict__ Clo,
                                               int Kk, int bstride, int roff){
  __shared__ us sm[SPLIT_IN ? 16384 : 8192];  // Ah@0, Bh@4096, (Al@8192, Bl@12288)
  const int tid = threadIdx.x, wid = tid >> 6, lane = tid & 63;
  const int l15 = lane & 15, l16 = lane >> 4;
  const int row0 = blockIdx.y * 128, col0 = blockIdx.x * 128;
  const int wr = (wid >> 1) * 64, wc = (wid & 1) * 64;
  f32x4 acc[4][4] = {};

  for (int k0 = 0; k0 < Kk; k0 += 32){
    for (int c = 0; c < 2; ++c){
      int i = c * 256 + tid;                           // 0..511: row=i>>2, k8=(i&3)*8
      size_t aoff = (size_t)(row0 + (i >> 2)) * Kk + k0 + (i & 3) * 8;
      size_t boff = (size_t)(col0 + (i >> 2)) * Kk + k0 + (i & 3) * 8;
      __builtin_amdgcn_global_load_lds((const __attribute__((address_space(1))) unsigned int*)(Ah + aoff),
        (__attribute__((address_space(3))) unsigned int*)&sm[c * 2048 + wid * 512], 16, 0, 0);
      __builtin_amdgcn_global_load_lds((const __attribute__((address_space(1))) unsigned int*)(Bth + boff),
        (__attribute__((address_space(3))) unsigned int*)&sm[4096 + c * 2048 + wid * 512], 16, 0, 0);
      if (SPLIT_IN){
        __builtin_amdgcn_global_load_lds((const __attribute__((address_space(1))) unsigned int*)(Al + aoff),
          (__attribute__((address_space(3))) unsigned int*)&sm[8192 + c * 2048 + wid * 512], 16, 0, 0);
        __builtin_amdgcn_global_load_lds((const __attribute__((address_space(1))) unsigned int*)(Btl + boff),
          (__attribute__((address_space(3))) unsigned int*)&sm[12288 + c * 2048 + wid * 512], 16, 0, 0);
      }
    }
    __syncthreads();
    bf16x8 afh[4], bfh[4];
    for (int m = 0; m < 4; m++) afh[m] = *(const bf16x8*)&sm[(wr + m * 16 + l15) * 32 + l16 * 8];
    for (int n = 0; n < 4; n++) bfh[n] = *(const bf16x8*)&sm[4096 + (wc + n * 16 + l15) * 32 + l16 * 8];
    if (SPLIT_IN){
      bf16x8 afl[4], bfl[4];
      for (int m = 0; m < 4; m++) afl[m] = *(const bf16x8*)&sm[8192 + (wr + m * 16 + l15) * 32 + l16 * 8];
      for (int n = 0; n < 4; n++) bfl[n] = *(const bf16x8*)&sm[12288 + (wc + n * 16 + l15) * 32 + l16 * 8];
      for (int m = 0; m < 4; m++)
        for (int n = 0; n < 4; n++){
          acc[m][n] = __builtin_amdgcn_mfma_f32_16x16x32_bf16(afh[m], bfh[n], acc[m][n], 0, 0, 0);
          acc[m][n] = __builtin_amdgcn_mfma_f32_16x16x32_bf16(afh[m], bfl[n], acc[m][n], 0, 0, 0);
          acc[m][n] = __builtin_amdgcn_mfma_f32_16x16x32_bf16(afl[m], bfh[n], acc[m][n], 0, 0, 0);
        }
    } else {
      for (int m = 0; m < 4; m++)
        for (int n = 0; n < 4; n++)
          acc[m][n] = __builtin_amdgcn_mfma_f32_16x16x32_bf16(afh[m], bfh[n], acc[m][n], 0, 0, 0);
    }
    __syncthreads();
  }

  for (int m = 0; m < 4; m++)
    for (int n = 0; n < 4; n++){
      int col = col0 + wc + n * 16 + l15;
      float bv = bias[col];
      if (TRANS_OUT){
        int r = row0 + wr + m * 16 + l16 * 4;          // j=0 base, 4 consecutive rows
        u16x4 o;
        for (int j = 0; j < 4; j++) o[j] = f2bf(acc[m][n][j] + bv);
        *(u16x4*)&((us*)Co)[((size_t)((r >> 11) * 1024 + col)) * 4096 + roff + (r & 2047)] = o;
      } else {
        for (int j = 0; j < 4; j++){
          int r = row0 + wr + m * 16 + l16 * 4 + j;
          size_t orow = (size_t)((r >> 11) * bstride + roff + (r & 2047));
          float v = acc[m][n][j] + bv;
          if (SPLIT_OUT){
            us h = f2bf(v);
            ((us*)Co)[orow * 1024 + col] = h;
            Clo[orow * 1024 + col] = f2bf(v - bf2f(h));
          } else {
            store_out(&Co[orow * 1024 + col], v);
          }
        }
      }
    }
}

// ---------------- fused attention (swapped-operand, split-precision QK^T) ----------------
// grid: B*H*(M/64); 4 waves; wave w owns q rows [w*16, w*16+16), q = l15 lane-local.
// S^T = mfma(K, Q): lane holds (q=l15, t = nf*16 + l16*4 + j) -> softmax nearly in-register.
// V stored transposed in global [2][1024 d][4096 t]; PV: O^T = mfma(V^T rows, P rows).
__global__ __launch_bounds__(256) void attn_kernel(const us* __restrict__ Qh, const us* __restrict__ Ql,
                                                   const us* __restrict__ Kh, const us* __restrict__ Kl,
                                                   const us* __restrict__ VT,
                                                   us* __restrict__ attno){
  __shared__ us Klh[64 * 72];
  __shared__ us Kll[64 * 72];
  __shared__ us Vt[64 * 72];
  __shared__ us Pl[4][16 * 72];
  const int tid = threadIdx.x, wid = tid >> 6, lane = tid & 63;
  const int l15 = lane & 15, l16 = lane >> 4;
  const int qt = blockIdx.x & 31;
  const int bh = blockIdx.x >> 5;
  const int h = bh & 15, b = bh >> 4;

  // Q fragments (second operand: lane reads row q=l15, contiguous d)
  bf16x8 qfh[2], qfl[2];
  {
    size_t qoff = (size_t)(b * MM + qt * 64 + wid * 16 + l15) * 1024 + h * 64 + l16 * 8;
    qfh[0] = *(const bf16x8*)(Qh + qoff);
    qfh[1] = *(const bf16x8*)(Qh + qoff + 32);
    qfl[0] = *(const bf16x8*)(Ql + qoff);
    qfl[1] = *(const bf16x8*)(Ql + qoff + 32);
  }

  // staging indices: thread covers 2 chunks per array
  const int i0 = tid, i1 = 256 + tid;
  const int kt0 = i0 >> 3, kd0 = (i0 & 7) * 8;
  const int kt1 = i1 >> 3, kd1 = (i1 & 7) * 8;
  // V^T: row d, 8 consecutive t
  const int vd0 = kt0, vt0 = kd0, vd1 = kt1, vt1 = kd1;

#define GK(t0_, t_, d_) (((size_t)(b * TT + (t0_) + (t_))) * 1024 + h * 64 + (d_))
#define GV(t0_, d_, t_) (((size_t)b * 1024 + h * 64 + (d_)) * 4096 + (t0_) + (t_))

  // prologue: stage tile 0
  uint4 rKh0 = *(const uint4*)(Kh + GK(0, kt0, kd0));
  uint4 rKh1 = *(const uint4*)(Kh + GK(0, kt1, kd1));
  uint4 rKl0 = *(const uint4*)(Kl + GK(0, kt0, kd0));
  uint4 rKl1 = *(const uint4*)(Kl + GK(0, kt1, kd1));
  uint4 rV0  = *(const uint4*)(VT + GV(0, vd0, vt0));
  uint4 rV1  = *(const uint4*)(VT + GV(0, vd1, vt1));
  *(uint4*)&Klh[kt0 * 72 + kd0] = rKh0;
  *(uint4*)&Klh[kt1 * 72 + kd1] = rKh1;
  *(uint4*)&Kll[kt0 * 72 + kd0] = rKl0;
  *(uint4*)&Kll[kt1 * 72 + kd1] = rKl1;
  *(uint4*)&Vt[vd0 * 72 + vt0] = rV0;
  *(uint4*)&Vt[vd1 * 72 + vt1] = rV1;
  __syncthreads();

  f32x4 acc2[4] = {};
  float mrow = -1e30f, lrow = 0.f;

  for (int t0 = 0; t0 < TT; t0 += 64){
    const bool pre = (t0 + 64 < TT);
    if (pre){
      rKh0 = *(const uint4*)(Kh + GK(t0 + 64, kt0, kd0));
      rKh1 = *(const uint4*)(Kh + GK(t0 + 64, kt1, kd1));
      rKl0 = *(const uint4*)(Kl + GK(t0 + 64, kt0, kd0));
      rKl1 = *(const uint4*)(Kl + GK(t0 + 64, kt1, kd1));
      rV0  = *(const uint4*)(VT + GV(t0 + 64, vd0, vt0));
      rV1  = *(const uint4*)(VT + GV(t0 + 64, vd1, vt1));
    }

    // S^T = K . Q^T (split): lane holds q=l15, t = nf*16 + l16*4 + j
    f32x4 sfr[4] = {};
    for (int kk = 0; kk < 2; kk++){
      for (int nf = 0; nf < 4; nf++){
        bf16x8 kfh = *(const bf16x8*)&Klh[(nf * 16 + l15) * 72 + kk * 32 + l16 * 8];
        bf16x8 kfl = *(const bf16x8*)&Kll[(nf * 16 + l15) * 72 + kk * 32 + l16 * 8];
        sfr[nf] = __builtin_amdgcn_mfma_f32_16x16x32_bf16(kfh, qfh[kk], sfr[nf], 0, 0, 0);
        sfr[nf] = __builtin_amdgcn_mfma_f32_16x16x32_bf16(kfl, qfh[kk], sfr[nf], 0, 0, 0);
        sfr[nf] = __builtin_amdgcn_mfma_f32_16x16x32_bf16(kfh, qfl[kk], sfr[nf], 0, 0, 0);
      }
    }

    // online softmax: per-lane 16 values of one q-row; cross-l16 via 2 shfl_xor
    float v = -1e30f;
    for (int nf = 0; nf < 4; nf++)
      for (int j = 0; j < 4; j++){
        sfr[nf][j] *= 0.125f;
        v = fmaxf(v, sfr[nf][j]);
      }
    v = fmaxf(v, __shfl_xor(v, 16, 64));
    v = fmaxf(v, __shfl_xor(v, 32, 64));
    float mn = fmaxf(mrow, v);
    float rs = __expf(mrow - mn);
    mrow = mn;
    float ts = 0.f;
    for (int nf = 0; nf < 4; nf++){
      u16x4 pw;
      for (int j = 0; j < 4; j++){
        float e = __expf(sfr[nf][j] - mn);
        ts += e;
        pw[j] = f2bf(e);
      }
      *(u16x4*)&Pl[wid][l15 * 72 + nf * 16 + l16 * 4] = pw;   // per-wave, no barrier
    }
    ts += __shfl_xor(ts, 16, 64);
    ts += __shfl_xor(ts, 32, 64);
    lrow = lrow * rs + ts;
    for (int nf = 0; nf < 4; nf++) acc2[nf] *= rs;

    // O^T += V^T . P^T : lane holds q=l15, d = nf*16 + l16*4 + j
    for (int kk = 0; kk < 2; kk++){
      bf16x8 pf = *(const bf16x8*)&Pl[wid][l15 * 72 + kk * 32 + l16 * 8];
      for (int nf = 0; nf < 4; nf++){
        bf16x8 vf = *(const bf16x8*)&Vt[(nf * 16 + l15) * 72 + kk * 32 + l16 * 8];
        acc2[nf] = __builtin_amdgcn_mfma_f32_16x16x32_bf16(vf, pf, acc2[nf], 0, 0, 0);
      }
    }

    __syncthreads();               // all waves done reading K/V LDS
    if (pre){
      *(uint4*)&Klh[kt0 * 72 + kd0] = rKh0;
      *(uint4*)&Klh[kt1 * 72 + kd1] = rKh1;
      *(uint4*)&Kll[kt0 * 72 + kd0] = rKl0;
      *(uint4*)&Kll[kt1 * 72 + kd1] = rKl1;
      *(uint4*)&Vt[vd0 * 72 + vt0] = rV0;
      *(uint4*)&Vt[vd1 * 72 + vt1] = rV1;
    }
    __syncthreads();
  }
#undef GK
#undef GV

  float inv = 1.f / lrow;
  for (int nf = 0; nf < 4; nf++){
    u16x4 o;
    for (int j = 0; j < 4; j++) o[j] = f2bf(acc2[nf][j] * inv);
    *(u16x4*)&attno[(size_t)(b * MM + qt * 64 + wid * 16 + l15) * 1024 + h * 64 + nf * 16 + l16 * 4] = o;
  }
}

extern "C" void kernel_launch(void* const* d_in, const int* in_sizes, int n_in,
                              void* d_out, int out_size, void* d_ws, size_t ws_size,
                              hipStream_t stream){
  const float* x      = (const float*)d_in[0];
  const float* data   = (const float*)d_in[1];
  const float* W_attn = (const float*)d_in[2];
  const float* b_attn = (const float*)d_in[3];
  const float* W_data = (const float*)d_in[4];
  const float* b_data = (const float*)d_in[5];
  const float* W_proj = (const float*)d_in[6];
  const float* b_proj = (const float*)d_in[7];
  float* out = (float*)d_out;

  char* ws = (char*)d_ws;
  us* xb_hi  = (us*)(ws + 0);            // 4096x1024 (8 MB each)
  us* xb_lo  = (us*)(ws + 8388608);
  us* db_hi  = (us*)(ws + 16777216);
  us* db_lo  = (us*)(ws + 25165824);
  us* Wat_hi = (us*)(ws + 33554432);     // 3072x1024 (6 MB each)
  us* Wat_lo = (us*)(ws + 39845888);
  us* Wdt_hi = (us*)(ws + 46137344);     // 2048x1024 (4 MB each)
  us* Wdt_lo = (us*)(ws + 50331648);
  us* Wpt_hi = (us*)(ws + 54525952);     // 1024x1024 (2 MB each)
  us* Wpt_lo = (us*)(ws + 56623104);
  us* Qh     = (us*)(ws + 58720256);     // [2][2048][1024] (8 MB each)
  us* Ql     = (us*)(ws + 67108864);
  us* Kh     = (us*)(ws + 75497472);     // [2][4096][1024] (16 MB each)
  us* Kl     = (us*)(ws + 92274688);
  us* VT     = (us*)(ws + 109051904);    // [2][1024][4096] transposed V (16 MB)
  us* attno  = (us*)(ws + 16777216);     // alias db_hi (db consumed before attn runs)

  split_cast<<<2048, 256, 0, stream>>>(x, xb_hi, xb_lo);
  split_cast<<<2048, 256, 0, stream>>>(data, db_hi, db_lo);
  transpose_split<<<dim3(96, 32), 256, 0, stream>>>(W_attn, Wat_hi, Wat_lo, 1024, 3072);
  transpose_split<<<dim3(64, 32), 256, 0, stream>>>(W_data, Wdt_hi, Wdt_lo, 1024, 2048);
  transpose_split<<<dim3(32, 32), 256, 0, stream>>>(W_proj, Wpt_hi, Wpt_lo, 1024, 1024);

  dim3 gg(8, 32);
  // q = x @ W_attn[:,0:1024]  (split in+out) -> Qh/Ql [2][2048][1024]
  gemm_bt<true, true, false, us><<<gg, 256, 0, stream>>>(xb_hi, xb_lo, Wat_hi, Wat_lo,
                                                  b_attn, Qh, Ql, 1024, 2048, 0);
  // k = x @ W_attn[:,1024:2048] -> Kh/Kl rows b*4096 + m
  gemm_bt<true, true, false, us><<<gg, 256, 0, stream>>>(xb_hi, xb_lo, Wat_hi + 1024 * 1024, Wat_lo + 1024 * 1024,
                                                  b_attn + 1024, Kh, Kl, 1024, 4096, 0);
  // v = x @ W_attn[:,2048:3072] -> V^T[b][d][t], t = m
  gemm_bt<false, false, true, us><<<gg, 256, 0, stream>>>(xb_hi, nullptr, Wat_hi + 2048 * 1024, nullptr,
                                                    b_attn + 2048, VT, nullptr, 1024, 0, 0);
  // k_data = data @ W_data[:,0:1024] -> Kh/Kl rows b*4096 + 2048 + n
  gemm_bt<true, true, false, us><<<gg, 256, 0, stream>>>(db_hi, db_lo, Wdt_hi, Wdt_lo,
                                                  b_data, Kh, Kl, 1024, 4096, 2048);
  // v_data = data @ W_data[:,1024:2048] -> V^T[b][d][2048 + t]
  gemm_bt<false, false, true, us><<<gg, 256, 0, stream>>>(db_hi, nullptr, Wdt_hi + 1024 * 1024, nullptr,
                                                    b_data + 1024, VT, nullptr, 1024, 0, 2048);

  attn_kernel<<<1024, 256, 0, stream>>>(Qh, Ql, Kh, Kl, VT, attno);

  gemm_bt<false, false, false, float><<<gg, 256, 0, stream>>>(attno, nullptr, Wpt_hi, nullptr,
                                                       b_proj, out, nullptr, 1024, 2048, 0);
}

// Round 4
// 413.829 us; speedup vs baseline: 1.5620x; 1.1478x over previous
//
#include <hip/hip_runtime.h>

typedef __bf16 bf16x8 __attribute__((ext_vector_type(8)));
typedef __bf16 bf16x4 __attribute__((ext_vector_type(4)));
typedef float f32x4 __attribute__((ext_vector_type(4)));
typedef float f32x16 __attribute__((ext_vector_type(16)));
typedef unsigned short u16x8 __attribute__((ext_vector_type(8)));
typedef unsigned short u16x4 __attribute__((ext_vector_type(4)));
typedef unsigned short us;

#define MM 2048
#define TT 4096

__device__ __forceinline__ us f2bf(float f){
  unsigned int u = __builtin_bit_cast(unsigned int, f);
  u = (u + 0x7fffu + ((u >> 16) & 1u)) >> 16;
  return (us)u;
}
__device__ __forceinline__ float bf2f(us u){
  unsigned int x = ((unsigned int)u) << 16;
  return __builtin_bit_cast(float, x);
}
__device__ __forceinline__ void store_out(us* p, float v){ *p = f2bf(v); }
__device__ __forceinline__ void store_out(float* p, float v){ *p = v; }

// ---------------- fp32 -> bf16 hi/lo split ----------------
__global__ __launch_bounds__(256) void split_cast(const float* __restrict__ in,
                                                  us* __restrict__ hi, us* __restrict__ lo){
  size_t i = ((size_t)blockIdx.x * 256 + threadIdx.x) * 8;
  float4 a = *(const float4*)(in + i);
  float4 b = *(const float4*)(in + i + 4);
  float v[8] = {a.x,a.y,a.z,a.w,b.x,b.y,b.z,b.w};
  u16x8 rh, rl;
  for (int j = 0; j < 8; j++){
    us h = f2bf(v[j]);
    rh[j] = h;
    rl[j] = f2bf(v[j] - bf2f(h));
  }
  *(u16x8*)(hi + i) = rh;
  *(u16x8*)(lo + i) = rl;
}

// ---------------- transpose + split: W[K][N] f32 -> Wt_hi/lo[N][K] bf16 ----------------
__global__ __launch_bounds__(256) void transpose_split(const float* __restrict__ W,
                                                       us* __restrict__ Wth, us* __restrict__ Wtl,
                                                       int K, int N){
  __shared__ float tile[32][33];
  int tx = threadIdx.x & 31, ty = threadIdx.x >> 5;   // 32 x 8
  int n0 = blockIdx.x * 32, k0 = blockIdx.y * 32;
  for (int r = 0; r < 32; r += 8)
    tile[ty + r][tx] = W[(size_t)(k0 + ty + r) * N + n0 + tx];
  __syncthreads();
  for (int r = 0; r < 32; r += 8){
    float v = tile[tx][ty + r];
    us h = f2bf(v);
    size_t idx = (size_t)(n0 + ty + r) * K + k0 + tx;
    Wth[idx] = h;
    Wtl[idx] = f2bf(v - bf2f(h));
  }
}

// ---------------- bf16 GEMM, B pre-transposed (Bt[N][K]), +bias ----------------
template<bool SPLIT_IN, bool SPLIT_OUT, bool TRANS_OUT, typename OutT>
__global__ __launch_bounds__(256) void gemm_bt(const us* __restrict__ Ah, const us* __restrict__ Al,
                                               const us* __restrict__ Bth, const us* __restrict__ Btl,
                                               const float* __restrict__ bias,
                                               OutT* __restrict__ Co, us* __restrict__ Clo,
                                               int Kk, int bstride, int roff){
  __shared__ us sm[SPLIT_IN ? 16384 : 8192];  // Ah@0, Bh@4096, (Al@8192, Bl@12288)
  const int tid = threadIdx.x, wid = tid >> 6, lane = tid & 63;
  const int l15 = lane & 15, l16 = lane >> 4;
  const int row0 = blockIdx.y * 128, col0 = blockIdx.x * 128;
  const int wr = (wid >> 1) * 64, wc = (wid & 1) * 64;
  f32x4 acc[4][4] = {};

  for (int k0 = 0; k0 < Kk; k0 += 32){
    for (int c = 0; c < 2; ++c){
      int i = c * 256 + tid;                           // 0..511: row=i>>2, k8=(i&3)*8
      size_t aoff = (size_t)(row0 + (i >> 2)) * Kk + k0 + (i & 3) * 8;
      size_t boff = (size_t)(col0 + (i >> 2)) * Kk + k0 + (i & 3) * 8;
      __builtin_amdgcn_global_load_lds((const __attribute__((address_space(1))) unsigned int*)(Ah + aoff),
        (__attribute__((address_space(3))) unsigned int*)&sm[c * 2048 + wid * 512], 16, 0, 0);
      __builtin_amdgcn_global_load_lds((const __attribute__((address_space(1))) unsigned int*)(Bth + boff),
        (__attribute__((address_space(3))) unsigned int*)&sm[4096 + c * 2048 + wid * 512], 16, 0, 0);
      if (SPLIT_IN){
        __builtin_amdgcn_global_load_lds((const __attribute__((address_space(1))) unsigned int*)(Al + aoff),
          (__attribute__((address_space(3))) unsigned int*)&sm[8192 + c * 2048 + wid * 512], 16, 0, 0);
        __builtin_amdgcn_global_load_lds((const __attribute__((address_space(1))) unsigned int*)(Btl + boff),
          (__attribute__((address_space(3))) unsigned int*)&sm[12288 + c * 2048 + wid * 512], 16, 0, 0);
      }
    }
    __syncthreads();
    bf16x8 afh[4], bfh[4];
    for (int m = 0; m < 4; m++) afh[m] = *(const bf16x8*)&sm[(wr + m * 16 + l15) * 32 + l16 * 8];
    for (int n = 0; n < 4; n++) bfh[n] = *(const bf16x8*)&sm[4096 + (wc + n * 16 + l15) * 32 + l16 * 8];
    if (SPLIT_IN){
      bf16x8 afl[4], bfl[4];
      for (int m = 0; m < 4; m++) afl[m] = *(const bf16x8*)&sm[8192 + (wr + m * 16 + l15) * 32 + l16 * 8];
      for (int n = 0; n < 4; n++) bfl[n] = *(const bf16x8*)&sm[12288 + (wc + n * 16 + l15) * 32 + l16 * 8];
      for (int m = 0; m < 4; m++)
        for (int n = 0; n < 4; n++){
          acc[m][n] = __builtin_amdgcn_mfma_f32_16x16x32_bf16(afh[m], bfh[n], acc[m][n], 0, 0, 0);
          acc[m][n] = __builtin_amdgcn_mfma_f32_16x16x32_bf16(afh[m], bfl[n], acc[m][n], 0, 0, 0);
          acc[m][n] = __builtin_amdgcn_mfma_f32_16x16x32_bf16(afl[m], bfh[n], acc[m][n], 0, 0, 0);
        }
    } else {
      for (int m = 0; m < 4; m++)
        for (int n = 0; n < 4; n++)
          acc[m][n] = __builtin_amdgcn_mfma_f32_16x16x32_bf16(afh[m], bfh[n], acc[m][n], 0, 0, 0);
    }
    __syncthreads();
  }

  for (int m = 0; m < 4; m++)
    for (int n = 0; n < 4; n++){
      int col = col0 + wc + n * 16 + l15;
      float bv = bias[col];
      if (TRANS_OUT){
        int r = row0 + wr + m * 16 + l16 * 4;          // j=0 base, 4 consecutive rows
        u16x4 o;
        for (int j = 0; j < 4; j++) o[j] = f2bf(acc[m][n][j] + bv);
        *(u16x4*)&((us*)Co)[((size_t)((r >> 11) * 1024 + col)) * 4096 + roff + (r & 2047)] = o;
      } else {
        for (int j = 0; j < 4; j++){
          int r = row0 + wr + m * 16 + l16 * 4 + j;
          size_t orow = (size_t)((r >> 11) * bstride + roff + (r & 2047));
          float v = acc[m][n][j] + bv;
          if (SPLIT_OUT){
            us h = f2bf(v);
            ((us*)Co)[orow * 1024 + col] = h;
            Clo[orow * 1024 + col] = f2bf(v - bf2f(h));
          } else {
            store_out(&Co[orow * 1024 + col], v);
          }
        }
      }
    }
}

// ---------------- fused attention: 32x32 MFMA, swapped operands, split QK^T ----------------
// grid: B*H*(M/128); 4 waves x 32 q-rows. Lane: q = qbase + (lane&31), hb = lane>>5.
// S^T frag ts: reg 4g+j -> t = ts*32 + 8g + 4*hb + j (C-layout m74/m101).
// A-operand (K / V^T rows): row = lane&31, k = hb*8 + i.
// B-operand (Q / P): col = lane&31, k = hb*8 + i.
__global__ __launch_bounds__(256) void attn_kernel(const us* __restrict__ Qh, const us* __restrict__ Ql,
                                                   const us* __restrict__ Kh, const us* __restrict__ Kl,
                                                   const us* __restrict__ VT,
                                                   us* __restrict__ attno){
  __shared__ us Klh[64 * 72];
  __shared__ us Kll[64 * 72];
  __shared__ us Vt[64 * 72];
  __shared__ us Pl[4][32 * 72];
  const int tid = threadIdx.x, wid = tid >> 6, lane = tid & 63;
  const int l31 = lane & 31, hb = lane >> 5, h8 = hb * 8;
  const int qt = blockIdx.x & 15;             // M/128 = 16
  const int bh = blockIdx.x >> 4;
  const int hd = (bh & 15) * 64, b = bh >> 4;
  const int qrow = qt * 128 + wid * 32 + l31;

  // Q fragments (B operand): lane holds Q[qrow][d = kk*16 + h8 + i]
  bf16x8 qfh[4], qfl[4];
  {
    const us* qp = Qh + (size_t)(b * MM + qrow) * 1024 + hd;
    const us* qq = Ql + (size_t)(b * MM + qrow) * 1024 + hd;
#pragma unroll
    for (int kk = 0; kk < 4; kk++){
      qfh[kk] = *(const bf16x8*)(qp + kk * 16 + h8);
      qfl[kk] = *(const bf16x8*)(qq + kk * 16 + h8);
    }
  }

  // staging: 256 threads x 2 chunks cover 64x64 per array
  const int i0 = tid, i1 = 256 + tid;
  const int kt0 = i0 >> 3, kd0 = (i0 & 7) * 8;
  const int kt1 = i1 >> 3, kd1 = (i1 & 7) * 8;

#define GK(t0_, t_, d_) (((size_t)(b * TT + (t0_) + (t_))) * 1024 + hd + (d_))
#define GV(t0_, d_, t_) (((size_t)b * 1024 + hd + (d_)) * 4096 + (t0_) + (t_))

  uint4 rKh0 = *(const uint4*)(Kh + GK(0, kt0, kd0));
  uint4 rKh1 = *(const uint4*)(Kh + GK(0, kt1, kd1));
  uint4 rKl0 = *(const uint4*)(Kl + GK(0, kt0, kd0));
  uint4 rKl1 = *(const uint4*)(Kl + GK(0, kt1, kd1));
  uint4 rV0  = *(const uint4*)(VT + GV(0, kt0, kd0));
  uint4 rV1  = *(const uint4*)(VT + GV(0, kt1, kd1));
  *(uint4*)&Klh[kt0 * 72 + kd0] = rKh0;
  *(uint4*)&Klh[kt1 * 72 + kd1] = rKh1;
  *(uint4*)&Kll[kt0 * 72 + kd0] = rKl0;
  *(uint4*)&Kll[kt1 * 72 + kd1] = rKl1;
  *(uint4*)&Vt[kt0 * 72 + kd0] = rV0;
  *(uint4*)&Vt[kt1 * 72 + kd1] = rV1;
  __syncthreads();

  f32x16 acc0 = {}, acc1 = {};
  float mrow = -1e30f, lrow = 0.f;
  const float cs = 0.125f * 1.44269504088896f;   // to log2 domain

  for (int t0 = 0; t0 < TT; t0 += 64){
    const bool pre = (t0 + 64 < TT);
    if (pre){
      rKh0 = *(const uint4*)(Kh + GK(t0 + 64, kt0, kd0));
      rKh1 = *(const uint4*)(Kh + GK(t0 + 64, kt1, kd1));
      rKl0 = *(const uint4*)(Kl + GK(t0 + 64, kt0, kd0));
      rKl1 = *(const uint4*)(Kl + GK(t0 + 64, kt1, kd1));
      rV0  = *(const uint4*)(VT + GV(t0 + 64, kt0, kd0));
      rV1  = *(const uint4*)(VT + GV(t0 + 64, kt1, kd1));
    }

    // S^T = K . Q^T (split): frag ts holds t = ts*32 + tloc, q = l31
    f32x16 sfr0 = {}, sfr1 = {};
    __builtin_amdgcn_s_setprio(1);
#pragma unroll
    for (int kk = 0; kk < 4; kk++){
      bf16x8 a0h = *(const bf16x8*)&Klh[l31 * 72 + kk * 16 + h8];
      bf16x8 a0l = *(const bf16x8*)&Kll[l31 * 72 + kk * 16 + h8];
      bf16x8 a1h = *(const bf16x8*)&Klh[(32 + l31) * 72 + kk * 16 + h8];
      bf16x8 a1l = *(const bf16x8*)&Kll[(32 + l31) * 72 + kk * 16 + h8];
      sfr0 = __builtin_amdgcn_mfma_f32_32x32x16_bf16(a0h, qfh[kk], sfr0, 0, 0, 0);
      sfr0 = __builtin_amdgcn_mfma_f32_32x32x16_bf16(a0l, qfh[kk], sfr0, 0, 0, 0);
      sfr0 = __builtin_amdgcn_mfma_f32_32x32x16_bf16(a0h, qfl[kk], sfr0, 0, 0, 0);
      sfr1 = __builtin_amdgcn_mfma_f32_32x32x16_bf16(a1h, qfh[kk], sfr1, 0, 0, 0);
      sfr1 = __builtin_amdgcn_mfma_f32_32x32x16_bf16(a1l, qfh[kk], sfr1, 0, 0, 0);
      sfr1 = __builtin_amdgcn_mfma_f32_32x32x16_bf16(a1h, qfl[kk], sfr1, 0, 0, 0);
    }
    __builtin_amdgcn_s_setprio(0);

    // online softmax in log2 domain: 32 values/lane for q=l31; one shfl over lane^32
    float v = -1e30f;
#pragma unroll
    for (int r = 0; r < 16; r++){
      sfr0[r] *= cs; sfr1[r] *= cs;
      v = fmaxf(v, fmaxf(sfr0[r], sfr1[r]));
    }
    v = fmaxf(v, __shfl_xor(v, 32, 64));
    float mn = fmaxf(mrow, v);
    float rs = __builtin_amdgcn_exp2f(mrow - mn);
    mrow = mn;
    float tsum = 0.f;
#pragma unroll
    for (int g = 0; g < 4; g++){
      bf16x4 w0, w1;
#pragma unroll
      for (int j = 0; j < 4; j++){
        float e0 = __builtin_amdgcn_exp2f(sfr0[4 * g + j] - mn);
        float e1 = __builtin_amdgcn_exp2f(sfr1[4 * g + j] - mn);
        tsum += e0 + e1;
        w0[j] = (__bf16)e0;
        w1[j] = (__bf16)e1;
      }
      *(u16x4*)&Pl[wid][l31 * 72 + 8 * g + 4 * hb]      = __builtin_bit_cast(u16x4, w0);
      *(u16x4*)&Pl[wid][l31 * 72 + 32 + 8 * g + 4 * hb] = __builtin_bit_cast(u16x4, w1);
    }
    tsum += __shfl_xor(tsum, 32, 64);
    lrow = lrow * rs + tsum;
#pragma unroll
    for (int r = 0; r < 16; r++){ acc0[r] *= rs; acc1[r] *= rs; }

    // O^T += V^T . P^T : A = V^T rows d, B = P (col=q, k=t)
    __builtin_amdgcn_s_setprio(1);
#pragma unroll
    for (int kk = 0; kk < 4; kk++){
      bf16x8 pf = *(const bf16x8*)&Pl[wid][l31 * 72 + kk * 16 + h8];
      bf16x8 v0 = *(const bf16x8*)&Vt[l31 * 72 + kk * 16 + h8];
      bf16x8 v1 = *(const bf16x8*)&Vt[(32 + l31) * 72 + kk * 16 + h8];
      acc0 = __builtin_amdgcn_mfma_f32_32x32x16_bf16(v0, pf, acc0, 0, 0, 0);
      acc1 = __builtin_amdgcn_mfma_f32_32x32x16_bf16(v1, pf, acc1, 0, 0, 0);
    }
    __builtin_amdgcn_s_setprio(0);

    __syncthreads();               // all waves done reading K/V/P LDS
    if (pre){
      *(uint4*)&Klh[kt0 * 72 + kd0] = rKh0;
      *(uint4*)&Klh[kt1 * 72 + kd1] = rKh1;
      *(uint4*)&Kll[kt0 * 72 + kd0] = rKl0;
      *(uint4*)&Kll[kt1 * 72 + kd1] = rKl1;
      *(uint4*)&Vt[kt0 * 72 + kd0] = rV0;
      *(uint4*)&Vt[kt1 * 72 + kd1] = rV1;
    }
    __syncthreads();
  }
#undef GK
#undef GV

  float inv = 1.f / lrow;
  us* op = attno + (size_t)(b * MM + qrow) * 1024 + hd;
#pragma unroll
  for (int g = 0; g < 4; g++){
    bf16x4 w0, w1;
#pragma unroll
    for (int j = 0; j < 4; j++){
      w0[j] = (__bf16)(acc0[4 * g + j] * inv);
      w1[j] = (__bf16)(acc1[4 * g + j] * inv);
    }
    *(u16x4*)&op[8 * g + 4 * hb]      = __builtin_bit_cast(u16x4, w0);
    *(u16x4*)&op[32 + 8 * g + 4 * hb] = __builtin_bit_cast(u16x4, w1);
  }
}

extern "C" void kernel_launch(void* const* d_in, const int* in_sizes, int n_in,
                              void* d_out, int out_size, void* d_ws, size_t ws_size,
                              hipStream_t stream){
  const float* x      = (const float*)d_in[0];
  const float* data   = (const float*)d_in[1];
  const float* W_attn = (const float*)d_in[2];
  const float* b_attn = (const float*)d_in[3];
  const float* W_data = (const float*)d_in[4];
  const float* b_data = (const float*)d_in[5];
  const float* W_proj = (const float*)d_in[6];
  const float* b_proj = (const float*)d_in[7];
  float* out = (float*)d_out;

  char* ws = (char*)d_ws;
  us* xb_hi  = (us*)(ws + 0);            // 4096x1024 (8 MB each)
  us* xb_lo  = (us*)(ws + 8388608);
  us* db_hi  = (us*)(ws + 16777216);
  us* db_lo  = (us*)(ws + 25165824);
  us* Wat_hi = (us*)(ws + 33554432);     // 3072x1024 (6 MB each)
  us* Wat_lo = (us*)(ws + 39845888);
  us* Wdt_hi = (us*)(ws + 46137344);     // 2048x1024 (4 MB each)
  us* Wdt_lo = (us*)(ws + 50331648);
  us* Wpt_hi = (us*)(ws + 54525952);     // 1024x1024 (2 MB each)
  us* Wpt_lo = (us*)(ws + 56623104);
  us* Qh     = (us*)(ws + 58720256);     // [2][2048][1024] (8 MB each)
  us* Ql     = (us*)(ws + 67108864);
  us* Kh     = (us*)(ws + 75497472);     // [2][4096][1024] (16 MB each)
  us* Kl     = (us*)(ws + 92274688);
  us* VT     = (us*)(ws + 109051904);    // [2][1024][4096] transposed V (16 MB)
  us* attno  = (us*)(ws + 16777216);     // alias db_hi (db consumed before attn runs)

  split_cast<<<2048, 256, 0, stream>>>(x, xb_hi, xb_lo);
  split_cast<<<2048, 256, 0, stream>>>(data, db_hi, db_lo);
  transpose_split<<<dim3(96, 32), 256, 0, stream>>>(W_attn, Wat_hi, Wat_lo, 1024, 3072);
  transpose_split<<<dim3(64, 32), 256, 0, stream>>>(W_data, Wdt_hi, Wdt_lo, 1024, 2048);
  transpose_split<<<dim3(32, 32), 256, 0, stream>>>(W_proj, Wpt_hi, Wpt_lo, 1024, 1024);

  dim3 gg(8, 32);
  // q = x @ W_attn[:,0:1024]  (split in+out) -> Qh/Ql [2][2048][1024]
  gemm_bt<true, true, false, us><<<gg, 256, 0, stream>>>(xb_hi, xb_lo, Wat_hi, Wat_lo,
                                                  b_attn, Qh, Ql, 1024, 2048, 0);
  // k = x @ W_attn[:,1024:2048] -> Kh/Kl rows b*4096 + m
  gemm_bt<true, true, false, us><<<gg, 256, 0, stream>>>(xb_hi, xb_lo, Wat_hi + 1024 * 1024, Wat_lo + 1024 * 1024,
                                                  b_attn + 1024, Kh, Kl, 1024, 4096, 0);
  // v = x @ W_attn[:,2048:3072] -> V^T[b][d][t], t = m
  gemm_bt<false, false, true, us><<<gg, 256, 0, stream>>>(xb_hi, nullptr, Wat_hi + 2048 * 1024, nullptr,
                                                    b_attn + 2048, VT, nullptr, 1024, 0, 0);
  // k_data = data @ W_data[:,0:1024] -> Kh/Kl rows b*4096 + 2048 + n
  gemm_bt<true, true, false, us><<<gg, 256, 0, stream>>>(db_hi, db_lo, Wdt_hi, Wdt_lo,
                                                  b_data, Kh, Kl, 1024, 4096, 2048);
  // v_data = data @ W_data[:,1024:2048] -> V^T[b][d][2048 + t]
  gemm_bt<false, false, true, us><<<gg, 256, 0, stream>>>(db_hi, nullptr, Wdt_hi + 1024 * 1024, nullptr,
                                                    b_data + 1024, VT, nullptr, 1024, 0, 2048);

  attn_kernel<<<512, 256, 0, stream>>>(Qh, Ql, Kh, Kl, VT, attno);

  gemm_bt<false, false, false, float><<<gg, 256, 0, stream>>>(attno, nullptr, Wpt_hi, nullptr,
                                                       b_proj, out, nullptr, 1024, 2048, 0);
}

// Round 5
// 355.715 us; speedup vs baseline: 1.8171x; 1.1634x over previous
//
#include <hip/hip_runtime.h>

typedef __bf16 bf16x8 __attribute__((ext_vector_type(8)));
typedef __bf16 bf16x4 __attribute__((ext_vector_type(4)));
typedef float f32x4 __attribute__((ext_vector_type(4)));
typedef float f32x16 __attribute__((ext_vector_type(16)));
typedef unsigned short u16x8 __attribute__((ext_vector_type(8)));
typedef unsigned short u16x4 __attribute__((ext_vector_type(4)));
typedef unsigned short us;

#define MM 2048
#define TT 4096

__device__ __forceinline__ us f2bf(float f){
  unsigned int u = __builtin_bit_cast(unsigned int, f);
  u = (u + 0x7fffu + ((u >> 16) & 1u)) >> 16;
  return (us)u;
}
__device__ __forceinline__ float bf2f(us u){
  unsigned int x = ((unsigned int)u) << 16;
  return __builtin_bit_cast(float, x);
}

#define GLDS(gp, lp) __builtin_amdgcn_global_load_lds( \
    (const __attribute__((address_space(1))) unsigned int*)(gp), \
    (__attribute__((address_space(3))) unsigned int*)(lp), 16, 0, 0)

// ---------------- fp32 -> bf16 hi/lo split ----------------
__global__ __launch_bounds__(256) void split_cast(const float* __restrict__ in,
                                                  us* __restrict__ hi, us* __restrict__ lo){
  size_t i = ((size_t)blockIdx.x * 256 + threadIdx.x) * 8;
  float4 a = *(const float4*)(in + i);
  float4 b = *(const float4*)(in + i + 4);
  float v[8] = {a.x,a.y,a.z,a.w,b.x,b.y,b.z,b.w};
  u16x8 rh, rl;
  for (int j = 0; j < 8; j++){
    us h = f2bf(v[j]);
    rh[j] = h;
    rl[j] = f2bf(v[j] - bf2f(h));
  }
  *(u16x8*)(hi + i) = rh;
  *(u16x8*)(lo + i) = rl;
}

// ---------------- transpose + split: W[K][N] f32 -> Wt_hi/lo[N][K] bf16 ----------------
__global__ __launch_bounds__(256) void transpose_split(const float* __restrict__ W,
                                                       us* __restrict__ Wth, us* __restrict__ Wtl,
                                                       int K, int N){
  __shared__ float tile[32][33];
  int tx = threadIdx.x & 31, ty = threadIdx.x >> 5;   // 32 x 8
  int n0 = blockIdx.x * 32, k0 = blockIdx.y * 32;
  for (int r = 0; r < 32; r += 8)
    tile[ty + r][tx] = W[(size_t)(k0 + ty + r) * N + n0 + tx];
  __syncthreads();
  for (int r = 0; r < 32; r += 8){
    float v = tile[tx][ty + r];
    us h = f2bf(v);
    size_t idx = (size_t)(n0 + ty + r) * K + k0 + tx;
    Wth[idx] = h;
    Wtl[idx] = f2bf(v - bf2f(h));
  }
}

// ---------------- fused projection GEMM (q/k/v or k_data/v_data) ----------------
// A [4096][1024] bf16 hi/lo; Bt [(3|2)*1024][1024] bf16 hi/lo (pre-transposed).
// region = (blockIdx.x>>3)+regbase: 0 -> Q (split, rows r), 1 -> K (split, rows
// (r>>11)*4096 + kroff + (r&2047)), 2 -> V (plain, transposed out to VT).
// 128x128 tile, BK=32, 4 waves (2x2), 16x16x32 MFMA.
__global__ __launch_bounds__(256) void gemm_fused(const us* __restrict__ Ah, const us* __restrict__ Al,
                                                  const us* __restrict__ Bth, const us* __restrict__ Btl,
                                                  const float* __restrict__ bias,
                                                  us* __restrict__ Qh, us* __restrict__ Ql,
                                                  us* __restrict__ Kh, us* __restrict__ Kl,
                                                  us* __restrict__ VT,
                                                  int regbase, int kroff){
  __shared__ us sm[16384];  // Ah@0, Bh@4096, Al@8192, Bl@12288
  const int tid = threadIdx.x, wid = tid >> 6, lane = tid & 63;
  const int l15 = lane & 15, l16 = lane >> 4;
  const int row0 = blockIdx.y * 128, col0 = blockIdx.x * 128;
  const int region = (blockIdx.x >> 3) + regbase;
  const bool split = (region < 2);
  const int wr = (wid >> 1) * 64, wc = (wid & 1) * 64;
  f32x4 acc[4][4] = {};

  for (int k0 = 0; k0 < 1024; k0 += 32){
    for (int c = 0; c < 2; ++c){
      int i = c * 256 + tid;                           // 0..511: row=i>>2, k8=(i&3)*8
      size_t aoff = (size_t)(row0 + (i >> 2)) * 1024 + k0 + (i & 3) * 8;
      size_t boff = (size_t)(col0 + (i >> 2)) * 1024 + k0 + (i & 3) * 8;
      GLDS(Ah + aoff, &sm[c * 2048 + wid * 512]);
      GLDS(Bth + boff, &sm[4096 + c * 2048 + wid * 512]);
      if (split){
        GLDS(Al + aoff, &sm[8192 + c * 2048 + wid * 512]);
        GLDS(Btl + boff, &sm[12288 + c * 2048 + wid * 512]);
      }
    }
    __syncthreads();
    bf16x8 afh[4], bfh[4];
    for (int m = 0; m < 4; m++) afh[m] = *(const bf16x8*)&sm[(wr + m * 16 + l15) * 32 + l16 * 8];
    for (int n = 0; n < 4; n++) bfh[n] = *(const bf16x8*)&sm[4096 + (wc + n * 16 + l15) * 32 + l16 * 8];
    if (split){
      bf16x8 afl[4], bfl[4];
      for (int m = 0; m < 4; m++) afl[m] = *(const bf16x8*)&sm[8192 + (wr + m * 16 + l15) * 32 + l16 * 8];
      for (int n = 0; n < 4; n++) bfl[n] = *(const bf16x8*)&sm[12288 + (wc + n * 16 + l15) * 32 + l16 * 8];
      for (int m = 0; m < 4; m++)
        for (int n = 0; n < 4; n++){
          acc[m][n] = __builtin_amdgcn_mfma_f32_16x16x32_bf16(afh[m], bfh[n], acc[m][n], 0, 0, 0);
          acc[m][n] = __builtin_amdgcn_mfma_f32_16x16x32_bf16(afh[m], bfl[n], acc[m][n], 0, 0, 0);
          acc[m][n] = __builtin_amdgcn_mfma_f32_16x16x32_bf16(afl[m], bfh[n], acc[m][n], 0, 0, 0);
        }
    } else {
      for (int m = 0; m < 4; m++)
        for (int n = 0; n < 4; n++)
          acc[m][n] = __builtin_amdgcn_mfma_f32_16x16x32_bf16(afh[m], bfh[n], acc[m][n], 0, 0, 0);
    }
    __syncthreads();
  }

  for (int m = 0; m < 4; m++)
    for (int n = 0; n < 4; n++){
      int gcol = col0 + wc + n * 16 + l15;
      int ocol = gcol & 1023;
      float bv = bias[gcol];
      if (region == 2){                    // V -> VT[b][d][t], vectorized over 4 rows
        int r = row0 + wr + m * 16 + l16 * 4;
        u16x4 o;
        for (int j = 0; j < 4; j++) o[j] = f2bf(acc[m][n][j] + bv);
        *(u16x4*)&VT[((size_t)((r >> 11) * 1024 + ocol)) * 4096 + kroff + (r & 2047)] = o;
      } else {
        us* Ph = (region == 0) ? Qh : Kh;
        us* Pllo = (region == 0) ? Ql : Kl;
        for (int j = 0; j < 4; j++){
          int r = row0 + wr + m * 16 + l16 * 4 + j;
          size_t orow = (region == 0) ? (size_t)r
                                      : (size_t)((r >> 11) * 4096 + kroff + (r & 2047));
          float v = acc[m][n][j] + bv;
          us h = f2bf(v);
          Ph[orow * 1024 + ocol] = h;
          Pllo[orow * 1024 + ocol] = f2bf(v - bf2f(h));
        }
      }
    }
}

// ---------------- output projection GEMM (plain, fp32 out) ----------------
__global__ __launch_bounds__(256) void gemm_proj(const us* __restrict__ Ah,
                                                 const us* __restrict__ Bth,
                                                 const float* __restrict__ bias,
                                                 float* __restrict__ Co){
  __shared__ us sm[8192];
  const int tid = threadIdx.x, wid = tid >> 6, lane = tid & 63;
  const int l15 = lane & 15, l16 = lane >> 4;
  const int row0 = blockIdx.y * 128, col0 = blockIdx.x * 128;
  const int wr = (wid >> 1) * 64, wc = (wid & 1) * 64;
  f32x4 acc[4][4] = {};

  for (int k0 = 0; k0 < 1024; k0 += 32){
    for (int c = 0; c < 2; ++c){
      int i = c * 256 + tid;
      size_t aoff = (size_t)(row0 + (i >> 2)) * 1024 + k0 + (i & 3) * 8;
      size_t boff = (size_t)(col0 + (i >> 2)) * 1024 + k0 + (i & 3) * 8;
      GLDS(Ah + aoff, &sm[c * 2048 + wid * 512]);
      GLDS(Bth + boff, &sm[4096 + c * 2048 + wid * 512]);
    }
    __syncthreads();
    bf16x8 afh[4], bfh[4];
    for (int m = 0; m < 4; m++) afh[m] = *(const bf16x8*)&sm[(wr + m * 16 + l15) * 32 + l16 * 8];
    for (int n = 0; n < 4; n++) bfh[n] = *(const bf16x8*)&sm[4096 + (wc + n * 16 + l15) * 32 + l16 * 8];
    for (int m = 0; m < 4; m++)
      for (int n = 0; n < 4; n++)
        acc[m][n] = __builtin_amdgcn_mfma_f32_16x16x32_bf16(afh[m], bfh[n], acc[m][n], 0, 0, 0);
    __syncthreads();
  }

  for (int m = 0; m < 4; m++)
    for (int n = 0; n < 4; n++){
      int col = col0 + wc + n * 16 + l15;
      float bv = bias[col];
      for (int j = 0; j < 4; j++){
        int r = row0 + wr + m * 16 + l16 * 4 + j;
        Co[(size_t)r * 1024 + col] = acc[m][n][j] + bv;
      }
    }
}

// ---------------- fused attention: 32x32 MFMA, swapped operands, split QK^T ----------------
// grid: B*H*(M/128); 4 waves x 32 q-rows. Lane: q = qbase + (lane&31), hb = lane>>5.
// S^T frag: reg 4g+j -> t = ts*32 + 8g + 4*hb + j (C-layout m74/m101).
// T13 defer-max: skip acc rescale while tile max <= mrow + 8 (log2 domain).
__global__ __launch_bounds__(256) void attn_kernel(const us* __restrict__ Qh, const us* __restrict__ Ql,
                                                   const us* __restrict__ Kh, const us* __restrict__ Kl,
                                                   const us* __restrict__ VT,
                                                   us* __restrict__ attno){
  __shared__ us Klh[64 * 72];
  __shared__ us Kll[64 * 72];
  __shared__ us Vt[64 * 72];
  __shared__ us Pl[4][32 * 72];
  const int tid = threadIdx.x, wid = tid >> 6, lane = tid & 63;
  const int l31 = lane & 31, hb = lane >> 5, h8 = hb * 8;
  const int qt = blockIdx.x & 15;             // M/128 = 16
  const int bh = blockIdx.x >> 4;
  const int hd = (bh & 15) * 64, b = bh >> 4;
  const int qrow = qt * 128 + wid * 32 + l31;

  // Q fragments (B operand): lane holds Q[qrow][d = kk*16 + h8 + i]
  bf16x8 qfh[4], qfl[4];
  {
    const us* qp = Qh + (size_t)(b * MM + qrow) * 1024 + hd;
    const us* qq = Ql + (size_t)(b * MM + qrow) * 1024 + hd;
#pragma unroll
    for (int kk = 0; kk < 4; kk++){
      qfh[kk] = *(const bf16x8*)(qp + kk * 16 + h8);
      qfl[kk] = *(const bf16x8*)(qq + kk * 16 + h8);
    }
  }

  const int i0 = tid, i1 = 256 + tid;
  const int kt0 = i0 >> 3, kd0 = (i0 & 7) * 8;
  const int kt1 = i1 >> 3, kd1 = (i1 & 7) * 8;

#define GK(t0_, t_, d_) (((size_t)(b * TT + (t0_) + (t_))) * 1024 + hd + (d_))
#define GV(t0_, d_, t_) (((size_t)b * 1024 + hd + (d_)) * 4096 + (t0_) + (t_))

  uint4 rKh0 = *(const uint4*)(Kh + GK(0, kt0, kd0));
  uint4 rKh1 = *(const uint4*)(Kh + GK(0, kt1, kd1));
  uint4 rKl0 = *(const uint4*)(Kl + GK(0, kt0, kd0));
  uint4 rKl1 = *(const uint4*)(Kl + GK(0, kt1, kd1));
  uint4 rV0  = *(const uint4*)(VT + GV(0, kt0, kd0));
  uint4 rV1  = *(const uint4*)(VT + GV(0, kt1, kd1));
  *(uint4*)&Klh[kt0 * 72 + kd0] = rKh0;
  *(uint4*)&Klh[kt1 * 72 + kd1] = rKh1;
  *(uint4*)&Kll[kt0 * 72 + kd0] = rKl0;
  *(uint4*)&Kll[kt1 * 72 + kd1] = rKl1;
  *(uint4*)&Vt[kt0 * 72 + kd0] = rV0;
  *(uint4*)&Vt[kt1 * 72 + kd1] = rV1;
  __syncthreads();

  f32x16 acc0 = {}, acc1 = {};
  float mrow = -1e30f, lrow = 0.f;
  const float cs = 0.125f * 1.44269504088896f;   // to log2 domain

  for (int t0 = 0; t0 < TT; t0 += 64){
    const bool pre = (t0 + 64 < TT);
    if (pre){
      rKh0 = *(const uint4*)(Kh + GK(t0 + 64, kt0, kd0));
      rKh1 = *(const uint4*)(Kh + GK(t0 + 64, kt1, kd1));
      rKl0 = *(const uint4*)(Kl + GK(t0 + 64, kt0, kd0));
      rKl1 = *(const uint4*)(Kl + GK(t0 + 64, kt1, kd1));
      rV0  = *(const uint4*)(VT + GV(t0 + 64, kt0, kd0));
      rV1  = *(const uint4*)(VT + GV(t0 + 64, kt1, kd1));
    }

    // S^T = K . Q^T (split): frag ts holds t = ts*32 + tloc, q = l31
    f32x16 sfr0 = {}, sfr1 = {};
    __builtin_amdgcn_s_setprio(1);
#pragma unroll
    for (int kk = 0; kk < 4; kk++){
      bf16x8 a0h = *(const bf16x8*)&Klh[l31 * 72 + kk * 16 + h8];
      bf16x8 a0l = *(const bf16x8*)&Kll[l31 * 72 + kk * 16 + h8];
      bf16x8 a1h = *(const bf16x8*)&Klh[(32 + l31) * 72 + kk * 16 + h8];
      bf16x8 a1l = *(const bf16x8*)&Kll[(32 + l31) * 72 + kk * 16 + h8];
      sfr0 = __builtin_amdgcn_mfma_f32_32x32x16_bf16(a0h, qfh[kk], sfr0, 0, 0, 0);
      sfr0 = __builtin_amdgcn_mfma_f32_32x32x16_bf16(a0l, qfh[kk], sfr0, 0, 0, 0);
      sfr0 = __builtin_amdgcn_mfma_f32_32x32x16_bf16(a0h, qfl[kk], sfr0, 0, 0, 0);
      sfr1 = __builtin_amdgcn_mfma_f32_32x32x16_bf16(a1h, qfh[kk], sfr1, 0, 0, 0);
      sfr1 = __builtin_amdgcn_mfma_f32_32x32x16_bf16(a1l, qfh[kk], sfr1, 0, 0, 0);
      sfr1 = __builtin_amdgcn_mfma_f32_32x32x16_bf16(a1h, qfl[kk], sfr1, 0, 0, 0);
    }
    __builtin_amdgcn_s_setprio(0);

    // online softmax (log2 domain), T13 defer-max
    float v = -1e30f;
#pragma unroll
    for (int r = 0; r < 16; r++){
      sfr0[r] *= cs; sfr1[r] *= cs;
      v = fmaxf(v, fmaxf(sfr0[r], sfr1[r]));
    }
    v = fmaxf(v, __shfl_xor(v, 32, 64));
    if (!__all(v <= mrow + 8.f)){
      float mn = fmaxf(mrow, v);
      float rs = __builtin_amdgcn_exp2f(mrow - mn);
      mrow = mn;
      lrow *= rs;
#pragma unroll
      for (int r = 0; r < 16; r++){ acc0[r] *= rs; acc1[r] *= rs; }
    }
    float mn = mrow;
    float tsum = 0.f;
#pragma unroll
    for (int g = 0; g < 4; g++){
      bf16x4 w0, w1;
#pragma unroll
      for (int j = 0; j < 4; j++){
        float e0 = __builtin_amdgcn_exp2f(sfr0[4 * g + j] - mn);
        float e1 = __builtin_amdgcn_exp2f(sfr1[4 * g + j] - mn);
        tsum += e0 + e1;
        w0[j] = (__bf16)e0;
        w1[j] = (__bf16)e1;
      }
      *(u16x4*)&Pl[wid][l31 * 72 + 8 * g + 4 * hb]      = __builtin_bit_cast(u16x4, w0);
      *(u16x4*)&Pl[wid][l31 * 72 + 32 + 8 * g + 4 * hb] = __builtin_bit_cast(u16x4, w1);
    }
    tsum += __shfl_xor(tsum, 32, 64);
    lrow += tsum;

    // O^T += V^T . P^T : A = V^T rows d, B = P (col=q, k=t)
    __builtin_amdgcn_s_setprio(1);
#pragma unroll
    for (int kk = 0; kk < 4; kk++){
      bf16x8 pf = *(const bf16x8*)&Pl[wid][l31 * 72 + kk * 16 + h8];
      bf16x8 v0 = *(const bf16x8*)&Vt[l31 * 72 + kk * 16 + h8];
      bf16x8 v1 = *(const bf16x8*)&Vt[(32 + l31) * 72 + kk * 16 + h8];
      acc0 = __builtin_amdgcn_mfma_f32_32x32x16_bf16(v0, pf, acc0, 0, 0, 0);
      acc1 = __builtin_amdgcn_mfma_f32_32x32x16_bf16(v1, pf, acc1, 0, 0, 0);
    }
    __builtin_amdgcn_s_setprio(0);

    __syncthreads();               // all waves done reading K/V/P LDS
    if (pre){
      *(uint4*)&Klh[kt0 * 72 + kd0] = rKh0;
      *(uint4*)&Klh[kt1 * 72 + kd1] = rKh1;
      *(uint4*)&Kll[kt0 * 72 + kd0] = rKl0;
      *(uint4*)&Kll[kt1 * 72 + kd1] = rKl1;
      *(uint4*)&Vt[kt0 * 72 + kd0] = rV0;
      *(uint4*)&Vt[kt1 * 72 + kd1] = rV1;
    }
    __syncthreads();
  }
#undef GK
#undef GV

  float inv = 1.f / lrow;
  us* op = attno + (size_t)(b * MM + qrow) * 1024 + hd;
#pragma unroll
  for (int g = 0; g < 4; g++){
    bf16x4 w0, w1;
#pragma unroll
    for (int j = 0; j < 4; j++){
      w0[j] = (__bf16)(acc0[4 * g + j] * inv);
      w1[j] = (__bf16)(acc1[4 * g + j] * inv);
    }
    *(u16x4*)&op[8 * g + 4 * hb]      = __builtin_bit_cast(u16x4, w0);
    *(u16x4*)&op[32 + 8 * g + 4 * hb] = __builtin_bit_cast(u16x4, w1);
  }
}

extern "C" void kernel_launch(void* const* d_in, const int* in_sizes, int n_in,
                              void* d_out, int out_size, void* d_ws, size_t ws_size,
                              hipStream_t stream){
  const float* x      = (const float*)d_in[0];
  const float* data   = (const float*)d_in[1];
  const float* W_attn = (const float*)d_in[2];
  const float* b_attn = (const float*)d_in[3];
  const float* W_data = (const float*)d_in[4];
  const float* b_data = (const float*)d_in[5];
  const float* W_proj = (const float*)d_in[6];
  const float* b_proj = (const float*)d_in[7];
  float* out = (float*)d_out;

  char* ws = (char*)d_ws;
  us* xb_hi  = (us*)(ws + 0);            // 4096x1024 (8 MB each)
  us* xb_lo  = (us*)(ws + 8388608);
  us* db_hi  = (us*)(ws + 16777216);
  us* db_lo  = (us*)(ws + 25165824);
  us* Wat_hi = (us*)(ws + 33554432);     // 3072x1024 (6 MB each)
  us* Wat_lo = (us*)(ws + 39845888);
  us* Wdt_hi = (us*)(ws + 46137344);     // 2048x1024 (4 MB each)
  us* Wdt_lo = (us*)(ws + 50331648);
  us* Wpt_hi = (us*)(ws + 54525952);     // 1024x1024 (2 MB each)
  us* Wpt_lo = (us*)(ws + 56623104);
  us* Qh     = (us*)(ws + 58720256);     // [2][2048][1024] (8 MB each)
  us* Ql     = (us*)(ws + 67108864);
  us* Kh     = (us*)(ws + 75497472);     // [2][4096][1024] (16 MB each)
  us* Kl     = (us*)(ws + 92274688);
  us* VT     = (us*)(ws + 109051904);    // [2][1024][4096] transposed V (16 MB)
  us* attno  = (us*)(ws + 16777216);     // alias db_hi (db consumed before attn runs)

  split_cast<<<2048, 256, 0, stream>>>(x, xb_hi, xb_lo);
  split_cast<<<2048, 256, 0, stream>>>(data, db_hi, db_lo);
  transpose_split<<<dim3(96, 32), 256, 0, stream>>>(W_attn, Wat_hi, Wat_lo, 1024, 3072);
  transpose_split<<<dim3(64, 32), 256, 0, stream>>>(W_data, Wdt_hi, Wdt_lo, 1024, 2048);
  transpose_split<<<dim3(32, 32), 256, 0, stream>>>(W_proj, Wpt_hi, Wpt_lo, 1024, 1024);

  // q,k,v = x @ W_attn (+b): regions 0,1,2 -> Qh/Ql, Kh/Kl@roff0, VT@roff0
  gemm_fused<<<dim3(24, 32), 256, 0, stream>>>(xb_hi, xb_lo, Wat_hi, Wat_lo, b_attn,
                                               Qh, Ql, Kh, Kl, VT, 0, 0);
  // k_data,v_data = data @ W_data (+b): regions 1,2 -> Kh/Kl@roff2048, VT@roff2048
  gemm_fused<<<dim3(16, 32), 256, 0, stream>>>(db_hi, db_lo, Wdt_hi, Wdt_lo, b_data,
                                               nullptr, nullptr, Kh, Kl, VT, 1, 2048);

  attn_kernel<<<512, 256, 0, stream>>>(Qh, Ql, Kh, Kl, VT, attno);

  gemm_proj<<<dim3(8, 32), 256, 0, stream>>>(attno, Wpt_hi, b_proj, out);
}